// Round 8
// baseline (356.665 us; speedup 1.0000x reference)
//
#include <hip/hip_runtime.h>
#include <cmath>
#include <complex>

// sr=16000, band 500-7000, order 8 -> 16 poles = 8 real 2nd-order sections.
#define NB    32
#define LX    262144
#define PAD   51                      // padlen = 3*17
#define LTOT  (LX + 2 * PAD)          // 262246
#define CM    32                      // samples per chunk (= per thread)
#define NC    8196                    // ceil(LTOT/CM)
#define LPAD  (NC * CM)               // 262272 (26 pad slots at reversed head)
#define CPB   256                     // chunks (threads) per tile/block
#define NTROW ((NC + CPB - 1) / CPB)  // 33 tiles per row
#define NP    8
#define LDS_STRIDE 34

struct CoeffsS { float a1[NP], a2[NP], b0[NP], b1[NP], c0; };
// lv[k][q] = (A_q^CM)^(2^k) = M0^(2^k), [m00 m01 m10 m11]; lv[8] = tile aggregate
struct LvS { float lv[9][NP][4]; };

// ---------------------------------------------------------------------------
// init: reset lookback flags + tickets (every launch!) and build mt[t][q]=M0^t.
__global__ void k_init(float4* __restrict__ mt, unsigned* __restrict__ flagsA,
                       unsigned* __restrict__ flagsB, unsigned* __restrict__ ticket,
                       LvS L) {
    int id = blockIdx.x * 256 + threadIdx.x;          // 0..2047
    if (id < NB * NTROW) { flagsA[id] = 0u; flagsB[id] = 0u; }
    if (id < 2) ticket[id] = 0u;
    int t = id >> 3, q = id & 7;
    float m0 = 1.f, m1 = 0.f, m2 = 0.f, m3 = 1.f;     // M0^t via binary exp
    for (int k = 0; k < 8; k++)
        if ((t >> k) & 1) {
            float a0 = L.lv[k][q][0], a1 = L.lv[k][q][1];
            float a2 = L.lv[k][q][2], a3 = L.lv[k][q][3];
            float n0 = a0 * m0 + a1 * m2, n1 = a0 * m1 + a1 * m3;
            float n2 = a2 * m0 + a3 * m2, n3 = a2 * m1 + a3 * m3;
            m0 = n0; m1 = n1; m2 = n2; m3 = n3;
        }
    mt[id] = make_float4(m0, m1, m2, m3);
}

// u[t] = ext[t] - ext[0] for the forward pass (odd extension of audio).
__device__ __forceinline__ void load_u_fwd(const float* __restrict__ x,
                                           float base, int t0, float (&u)[CM]) {
    if (t0 >= PAD && t0 + CM <= PAD + LX) {
        const float* xs = x + (t0 - PAD);
#pragma unroll
        for (int m = 0; m < CM / 4; m++) {
            float4 v = *reinterpret_cast<const float4*>(xs + 4 * m);
            u[4 * m] = v.x - base; u[4 * m + 1] = v.y - base;
            u[4 * m + 2] = v.z - base; u[4 * m + 3] = v.w - base;
        }
    } else {
#pragma unroll
        for (int i = 0; i < CM; i++) {
            int t = t0 + i;
            float e;
            if (t < PAD)            e = 2.0f * x[0] - x[PAD - t];
            else if (t < PAD + LX)  e = x[t - PAD];
            else if (t < LTOT)      e = 2.0f * x[LX - 1] - x[2 * LX + PAD - 2 - t];
            else                    e = base;   // u=0 tail continuation
            u[i] = e - base;
        }
    }
}

// ---------------------------------------------------------------------------
// One filtfilt direction in a single kernel: local states -> block scan ->
// decoupled lookback (agent-scope atomics) -> replay -> coalesced store.
// PASS 0: in=audio, out=ybuf (reversed).  PASS 1: in=ybuf, out=final (trim).
template <int PASS>
__global__ __launch_bounds__(256) void k_pass(
    const float* __restrict__ in, float* __restrict__ outp,
    const float4* __restrict__ mt,
    unsigned* __restrict__ flags, unsigned long long* __restrict__ agg,
    unsigned long long* __restrict__ pref, unsigned* __restrict__ ticket,
    CoeffsS C, LvS L) {
    __shared__ __align__(16) float lds[CPB * LDS_STRIDE];   // staging (aliases sc2)
    __shared__ float2 xb[NP];
    __shared__ unsigned vid_s;
    float2* sc2 = reinterpret_cast<float2*>(lds);           // sc2[q*256 + t], 16KB
    int tid = threadIdx.x;
    if (tid == 0) vid_s = atomicAdd(ticket, 1u);
    __syncthreads();
    unsigned vid = vid_s;
    int b = vid & (NB - 1);
    int trow = (int)(vid >> 5);
    int c = trow * CPB + tid;
    bool active = c < NC;

    // ---- phase 1: load u (kept in registers), local chunk states ----
    float u[CM];
    if (PASS == 0) {
        const float* x = in + (size_t)b * LX;
        float base = 2.0f * x[0] - x[PAD];
        load_u_fwd(x, base, c * CM, u);      // safe for inactive (no OOB loads)
    } else {
        const float* yb = in + (size_t)b * LPAD;
        float base = yb[26];                 // = y[LTOT-1]
        if (active) {
#pragma unroll
            for (int m = 0; m < CM / 4; m++) {
                float4 v = *reinterpret_cast<const float4*>(yb + (size_t)c * CM + 4 * m);
                u[4 * m] = v.x - base; u[4 * m + 1] = v.y - base;
                u[4 * m + 2] = v.z - base; u[4 * m + 3] = v.w - base;
            }
            if (c == 0) {                    // 26 reversed-pad slots -> u = 0
#pragma unroll
                for (int i = 0; i < 26; i++) u[i] = 0.f;
            }
        } else {
#pragma unroll
            for (int i = 0; i < CM; i++) u[i] = 0.f;
        }
    }
    float w1[NP], w2[NP];
#pragma unroll
    for (int q = 0; q < NP; q++) { w1[q] = 0.f; w2[q] = 0.f; }
#pragma unroll
    for (int i = 0; i < CM; i++) {
        float uu = u[i];
#pragma unroll
        for (int q = 0; q < NP; q++) {
            float wt = fmaf(C.a1[q], w1[q], fmaf(C.a2[q], w2[q], uu));
            w2[q] = w1[q]; w1[q] = wt;
        }
    }

    // ---- phase 2: block-level Hillis-Steele affine scan over chunks ----
    // combine multipliers are powers of M0 = A^CM (chunk transition!)
#pragma unroll
    for (int q = 0; q < NP; q++) sc2[q * 256 + tid] = make_float2(w1[q], w2[q]);
    __syncthreads();
#pragma unroll
    for (int k = 0; k < 8; k++) {
        int d = 1 << k;
        float2 o[NP];
        if (tid >= d) {
#pragma unroll
            for (int q = 0; q < NP; q++) o[q] = sc2[q * 256 + tid - d];
        }
        __syncthreads();
        if (tid >= d) {
#pragma unroll
            for (int q = 0; q < NP; q++) {
                w1[q] = fmaf(L.lv[k][q][0], o[q].x, fmaf(L.lv[k][q][1], o[q].y, w1[q]));
                w2[q] = fmaf(L.lv[k][q][2], o[q].x, fmaf(L.lv[k][q][3], o[q].y, w2[q]));
            }
        }
#pragma unroll
        for (int q = 0; q < NP; q++) sc2[q * 256 + tid] = make_float2(w1[q], w2[q]);
        __syncthreads();
    }
    float e1[NP], e2[NP];                    // exclusive prefix (entering own chunk)
#pragma unroll
    for (int q = 0; q < NP; q++) {
        float2 ev = (tid > 0) ? sc2[q * 256 + tid - 1] : make_float2(0.f, 0.f);
        e1[q] = ev.x; e2[q] = ev.y;
    }

    // ---- phase 3: publish aggregate, decoupled lookback, publish prefix ----
    if (tid < NP) {
        int q = tid;
        float2 Fv = sc2[q * 256 + 255];      // tile aggregate (from zero state)
        union { float2 f; unsigned long long u; } pk;
        pk.f = Fv;
        __hip_atomic_store(&agg[(size_t)vid * NP + q], pk.u,
                           __ATOMIC_RELAXED, __HIP_MEMORY_SCOPE_AGENT);
        __threadfence();
        if (q == 0)
            __hip_atomic_store(&flags[vid], 1u, __ATOMIC_RELEASE, __HIP_MEMORY_SCOPE_AGENT);
        float X1 = 0.f, X2 = 0.f;
        if (trow > 0) {
            float P0 = 1.f, P1 = 0.f, P2 = 0.f, P3 = 1.f;   // (M0^256)^k accum
            float B0 = L.lv[8][q][0], B1 = L.lv[8][q][1];   // tile transition M0^256
            float B2 = L.lv[8][q][2], B3 = L.lv[8][q][3];
            for (int j = trow - 1; j >= 0; --j) {
                unsigned pv = (unsigned)(j * NB + b);
                unsigned f;
                do {
                    f = __hip_atomic_load(&flags[pv], __ATOMIC_ACQUIRE,
                                          __HIP_MEMORY_SCOPE_AGENT);
                    if (!f) __builtin_amdgcn_s_sleep(4);
                } while (!f);
                const unsigned long long* src =
                    (f == 2u) ? &pref[(size_t)pv * NP + q] : &agg[(size_t)pv * NP + q];
                union { unsigned long long u; float2 f2; } up;
                up.u = __hip_atomic_load(src, __ATOMIC_RELAXED, __HIP_MEMORY_SCOPE_AGENT);
                X1 = fmaf(P0, up.f2.x, fmaf(P1, up.f2.y, X1));
                X2 = fmaf(P2, up.f2.x, fmaf(P3, up.f2.y, X2));
                if (f == 2u) break;
                float n0 = P0 * B0 + P1 * B2, n1 = P0 * B1 + P1 * B3;
                float n2 = P2 * B0 + P3 * B2, n3 = P2 * B1 + P3 * B3;
                P0 = n0; P1 = n1; P2 = n2; P3 = n3;
            }
        }
        float p1 = fmaf(L.lv[8][q][0], X1, fmaf(L.lv[8][q][1], X2, Fv.x));
        float p2 = fmaf(L.lv[8][q][2], X1, fmaf(L.lv[8][q][3], X2, Fv.y));
        pk.f = make_float2(p1, p2);
        __hip_atomic_store(&pref[(size_t)vid * NP + q], pk.u,
                           __ATOMIC_RELAXED, __HIP_MEMORY_SCOPE_AGENT);
        __threadfence();
        if (q == 0)
            __hip_atomic_store(&flags[vid], 2u, __ATOMIC_RELEASE, __HIP_MEMORY_SCOPE_AGENT);
        xb[q] = make_float2(X1, X2);
    }
    __syncthreads();

    // ---- phase 4: entering state = E + M0^tid * X; replay; stage; store ----
    if (active) {
        float4 m[NP];
#pragma unroll
        for (int q = 0; q < NP; q++) m[q] = mt[tid * NP + q];   // M0^tid per section
#pragma unroll
        for (int q = 0; q < NP; q++) {
            float2 X = xb[q];
            w1[q] = fmaf(m[q].x, X.x, fmaf(m[q].y, X.y, e1[q]));
            w2[q] = fmaf(m[q].z, X.x, fmaf(m[q].w, X.y, e2[q]));
        }
#pragma unroll
        for (int i = 0; i < CM; i++) {
            float uu = u[i];
            float y = C.c0 * uu;
#pragma unroll
            for (int q = 0; q < NP; q++) {
                float wt = fmaf(C.a1[q], w1[q], fmaf(C.a2[q], w2[q], uu));
                y = fmaf(C.b0[q], wt, fmaf(C.b1[q], w1[q], y));
                w2[q] = w1[q]; w1[q] = wt;
            }
            u[i] = y;                        // in-place: u now holds y
        }
        if (PASS == 0) {                     // stage y into LDS row
#pragma unroll
            for (int k = 0; k < CM / 2; k++)
                *reinterpret_cast<float2*>(&lds[tid * LDS_STRIDE + 2 * k]) =
                    make_float2(u[2 * k], u[2 * k + 1]);
        } else {
#pragma unroll
            for (int i = 0; i < CM; i++) lds[tid * LDS_STRIDE + i] = u[i];
        }
    }
    __syncthreads();
    int nch = NC - trow * CPB; if (nch > CPB) nch = CPB;
    if (PASS == 0) {
        // cooperative coalesced REVERSED store into ybuf
        float4* ybase = reinterpret_cast<float4*>(
            outp + (size_t)b * LPAD + (size_t)(NC - trow * CPB - nch) * CM);
#pragma unroll
        for (int m = 0; m < 8; m++) {
            int o4 = m * CPB + tid;
            if (o4 < nch * 8) {
                int ts = nch - 1 - (o4 >> 3);
                int ih = 31 - 4 * (o4 & 7);
                float2 a  = *reinterpret_cast<const float2*>(&lds[ts * LDS_STRIDE + ih - 1]);
                float2 b2 = *reinterpret_cast<const float2*>(&lds[ts * LDS_STRIDE + ih - 3]);
                ybase[o4] = make_float4(a.y, a.x, b2.y, b2.x);
            }
        }
    } else {
        // out[j] = yB[t], j = 262220 - t  (un-reverse + trim PAD)
        float* ob = outp + (size_t)b * LX;
        int J0 = (LTOT - 1 - PAD + 26) - trow * (CPB * CM);
#pragma unroll
        for (int m = 0; m < CM; m++) {
            int o = m * CPB + tid;
            if (o < nch * CM) {
                int j = J0 - o;
                if (j >= 0 && j < LX)
                    ob[j] = lds[(o >> 5) * LDS_STRIDE + (o & 31)];
            }
        }
    }
}

// ---------------------------------------------------------------------------
// Host: scipy butter(8,[500,7000]/8000,'bandpass') -> real 2nd-order sections
// + CHUNK-transition (A^CM) matrix power levels (f64, cast to f32).
static void compute_coeffs(CoeffsS& C, LvS& L) {
    using cd = std::complex<double>;
    const int N = 8;
    const double sr = 16000.0, lo = 500.0, hi = 7000.0, fs = 2.0;
    double w0 = 2.0 * fs * std::tan(M_PI * (2.0 * lo / sr) / fs);
    double w1 = 2.0 * fs * std::tan(M_PI * (2.0 * hi / sr) / fs);
    double bw = w1 - w0, wo = std::sqrt(w0 * w1);
    cd pbp[16];
    for (int k = 0; k < N; k++) {
        int m = -N + 1 + 2 * k;
        cd pl = -std::exp(cd(0.0, M_PI * m / (2.0 * N)));
        pl *= bw / 2.0;
        cd s = std::sqrt(pl * pl - cd(wo * wo, 0.0));
        pbp[k] = pl + s; pbp[k + N] = pl - s;
    }
    double kbp = std::pow(bw, (double)N);
    const double fs2 = 4.0;
    cd pd[16], denom = 1.0;
    for (int i = 0; i < 16; i++) {
        pd[i] = (cd(fs2, 0.0) + pbp[i]) / (cd(fs2, 0.0) - pbp[i]);
        denom *= (cd(fs2, 0.0) - pbp[i]);
    }
    double kd = kbp * std::real(cd(std::pow(fs2, 8.0), 0.0) / denom);
    cd prodp = 1.0;
    for (int i = 0; i < 16; i++) prodp *= pd[i];
    cd c0 = cd(kd, 0.0) / prodp;
    int n = 0;
    for (int i = 0; i < 16; i++) {
        if (pd[i].imag() <= 0.0) continue;
        cd inv = 1.0 / pd[i];
        cd t1 = cd(1.0, 0.0) - inv, t2 = cd(1.0, 0.0) + inv;
        cd numr = cd(kd, 0.0);
        for (int k = 0; k < 8; k++) numr *= t1;
        for (int k = 0; k < 8; k++) numr *= t2;
        cd den = 1.0;
        for (int j = 0; j < 16; j++)
            if (j != i) den *= (cd(1.0, 0.0) - pd[j] * inv);
        cd r2 = 2.0 * numr / den;             // conjugate pair folded
        if (n < NP) {
            double a1 = 2.0 * pd[i].real();
            double a2 = -std::norm(pd[i]);
            C.a1[n] = (float)a1; C.a2[n] = (float)a2;
            C.b0[n] = (float)r2.real();
            C.b1[n] = (float)(-(r2.real() * pd[i].real() + r2.imag() * pd[i].imag()));
            // A = [[a1,a2],[1,0]]; M0 = A^CM (chunk transition)
            double M[4] = { a1, a2, 1.0, 0.0 };
            for (int s = 0; s < 5; s++) {     // A^2, A^4, ..., A^32
                double q0 = M[0] * M[0] + M[1] * M[2], q1 = M[0] * M[1] + M[1] * M[3];
                double q2 = M[2] * M[0] + M[3] * M[2], q3 = M[2] * M[1] + M[3] * M[3];
                M[0] = q0; M[1] = q1; M[2] = q2; M[3] = q3;
            }
            for (int k = 0; k < 9; k++) {     // lv[k] = M0^(2^k), k=0..8
                for (int j = 0; j < 4; j++) L.lv[k][n][j] = (float)M[j];
                double q0 = M[0] * M[0] + M[1] * M[2], q1 = M[0] * M[1] + M[1] * M[3];
                double q2 = M[2] * M[0] + M[3] * M[2], q3 = M[2] * M[1] + M[3] * M[3];
                M[0] = q0; M[1] = q1; M[2] = q2; M[3] = q3;
            }
            n++;
        }
    }
    C.c0 = (float)c0.real();
}

extern "C" void kernel_launch(void* const* d_in, const int* in_sizes, int n_in,
                              void* d_out, int out_size, void* d_ws, size_t ws_size,
                              hipStream_t stream) {
    const float* audio = (const float*)d_in[0];
    float* out = (float*)d_out;

    CoeffsS C; LvS L;
    compute_coeffs(C, L);

    // workspace carve-up (~34 MB)
    char* ws = (char*)d_ws;
    size_t o = 0;
    auto alloc = [&](size_t bytes) { size_t r = o; o += (bytes + 255) & ~(size_t)255; return r; };
    float*    ybuf   = (float*)(ws + alloc((size_t)NB * LPAD * sizeof(float)));
    float4*   mt     = (float4*)(ws + alloc(2048 * sizeof(float4)));
    unsigned* flagsA = (unsigned*)(ws + alloc(NB * NTROW * sizeof(unsigned)));
    unsigned* flagsB = (unsigned*)(ws + alloc(NB * NTROW * sizeof(unsigned)));
    unsigned long long* aggA  = (unsigned long long*)(ws + alloc((size_t)NB * NTROW * NP * 8));
    unsigned long long* prefA = (unsigned long long*)(ws + alloc((size_t)NB * NTROW * NP * 8));
    unsigned long long* aggB  = (unsigned long long*)(ws + alloc((size_t)NB * NTROW * NP * 8));
    unsigned long long* prefB = (unsigned long long*)(ws + alloc((size_t)NB * NTROW * NP * 8));
    unsigned* ticket = (unsigned*)(ws + alloc(256));

    k_init<<<8, 256, 0, stream>>>(mt, flagsA, flagsB, ticket, L);
    k_pass<0><<<NB * NTROW, 256, 0, stream>>>(audio, ybuf, mt, flagsA, aggA, prefA,
                                              ticket + 0, C, L);
    k_pass<1><<<NB * NTROW, 256, 0, stream>>>(ybuf, out, mt, flagsB, aggB, prefB,
                                              ticket + 1, C, L);
}

// Round 9
// 102.784 us; speedup vs baseline: 3.4701x; 3.4701x over previous
//
#include <hip/hip_runtime.h>
#include <cmath>
#include <complex>

// sr=16000, band 500-7000, order 8 -> 16 poles = 8 real 2nd-order sections.
#define NB    32
#define LX    262144
#define PAD   51                      // padlen = 3*17
#define LTOT  (LX + 2 * PAD)          // 262246
#define CM    32                      // samples per chunk (= per thread)
#define F_PAD 8090                    // zero-input front pad
#define LPAD  (LTOT + F_PAD)          // 270336 = 33 * 8192 (tile-aligned!)
#define NCK   (LPAD / CM)             // 8448 chunks per row (all full)
#define CPB   256                     // chunks (threads) per tile
#define TILE  (CPB * CM)              // 8192 samples per tile
#define NTROW (LPAD / TILE)           // 33 tiles per row
#define NP    8
#define LDS_STRIDE 34

struct CoeffsS { float a1[NP], a2[NP], b0[NP], b1[NP], c0; };
// lv[k][q] = (A_q^CM)^(2^k) = M0^(2^k); lv[8] = M0^256 = tile transition
struct LvS { float lv[9][NP][4]; };

// ---------------------------------------------------------------------------
// init: build mt[t][q] = M0^t (t=0..255) via binary exponentiation.
__global__ void k_init(float4* __restrict__ mt, LvS L) {
    int id = blockIdx.x * 256 + threadIdx.x;          // 0..2047
    int t = id >> 3, q = id & 7;
    float m0 = 1.f, m1 = 0.f, m2 = 0.f, m3 = 1.f;
    for (int k = 0; k < 8; k++)
        if ((t >> k) & 1) {
            float a0 = L.lv[k][q][0], a1 = L.lv[k][q][1];
            float a2 = L.lv[k][q][2], a3 = L.lv[k][q][3];
            float n0 = a0 * m0 + a1 * m2, n1 = a0 * m1 + a1 * m3;
            float n2 = a2 * m0 + a3 * m2, n3 = a2 * m1 + a3 * m3;
            m0 = n0; m1 = n1; m2 = n2; m3 = n3;
        }
    mt[id] = make_float4(m0, m1, m2, m3);
}

// ---------------------------------------------------------------------------
// u-loaders. PASS A: global sample t' = c*CM + i, real time t = t' - F_PAD;
// u = 0 in the front pad, else ext[t] - ext[0] (odd extension of audio).
__device__ __forceinline__ void load_uA(const float* __restrict__ x,
                                        float base, int c, float (&u)[CM]) {
    int t0 = c * CM - F_PAD;
    if (t0 >= PAD && t0 + CM <= PAD + LX) {
        const float* xs = x + (t0 - PAD);
#pragma unroll
        for (int m = 0; m < CM / 4; m++) {
            float4 v = *reinterpret_cast<const float4*>(xs + 4 * m);
            u[4 * m] = v.x - base; u[4 * m + 1] = v.y - base;
            u[4 * m + 2] = v.z - base; u[4 * m + 3] = v.w - base;
        }
    } else {
#pragma unroll
        for (int i = 0; i < CM; i++) {
            int t = t0 + i;
            float uu;
            if (t < 0) uu = 0.f;                        // front pad
            else {
                float e;
                if (t < PAD)            e = 2.0f * x[0] - x[PAD - t];
                else if (t < PAD + LX)  e = x[t - PAD];
                else                    e = 2.0f * x[LX - 1] - x[2 * LX + PAD - 2 - t];
                uu = e - base;
            }
            u[i] = uu;
        }
    }
}

// PASS B: in = ybuf row (reversed y); base = ybuf[0] = y[LTOT-1].
__device__ __forceinline__ void load_uB(const float* __restrict__ yb,
                                        float base, int c, float (&u)[CM]) {
#pragma unroll
    for (int m = 0; m < CM / 4; m++) {
        float4 v = *reinterpret_cast<const float4*>(yb + (size_t)c * CM + 4 * m);
        u[4 * m] = v.x - base; u[4 * m + 1] = v.y - base;
        u[4 * m + 2] = v.z - base; u[4 * m + 3] = v.w - base;
    }
}

// local chunk recurrence from zero state (shared by both kernels)
__device__ __forceinline__ void local_states(const float (&u)[CM], const CoeffsS& C,
                                             float (&w1)[NP], float (&w2)[NP]) {
#pragma unroll
    for (int q = 0; q < NP; q++) { w1[q] = 0.f; w2[q] = 0.f; }
#pragma unroll
    for (int i = 0; i < CM; i++) {
        float uu = u[i];
#pragma unroll
        for (int q = 0; q < NP; q++) {
            float wt = fmaf(C.a1[q], w1[q], fmaf(C.a2[q], w2[q], uu));
            w2[q] = w1[q]; w1[q] = wt;
        }
    }
}

// block-level Hillis-Steele inclusive affine scan over 256 chunk states
__device__ __forceinline__ void block_scan(float2* sc2, int tid, const LvS& L,
                                           float (&w1)[NP], float (&w2)[NP]) {
#pragma unroll
    for (int q = 0; q < NP; q++) sc2[q * 256 + tid] = make_float2(w1[q], w2[q]);
    __syncthreads();
#pragma unroll
    for (int k = 0; k < 8; k++) {
        int d = 1 << k;
        float2 o[NP];
        if (tid >= d) {
#pragma unroll
            for (int q = 0; q < NP; q++) o[q] = sc2[q * 256 + tid - d];
        }
        __syncthreads();
        if (tid >= d) {
#pragma unroll
            for (int q = 0; q < NP; q++) {
                w1[q] = fmaf(L.lv[k][q][0], o[q].x, fmaf(L.lv[k][q][1], o[q].y, w1[q]));
                w2[q] = fmaf(L.lv[k][q][2], o[q].x, fmaf(L.lv[k][q][3], o[q].y, w2[q]));
            }
        }
#pragma unroll
        for (int q = 0; q < NP; q++) sc2[q * 256 + tid] = make_float2(w1[q], w2[q]);
        __syncthreads();
    }
}

// ---------------------------------------------------------------------------
// K1: per-tile aggregates (state after the tile's 8192 samples, zero init).
template <int PASS>
__global__ __launch_bounds__(256) void k_agg(const float* __restrict__ in,
                                             float2* __restrict__ agg,
                                             CoeffsS C, LvS L) {
    __shared__ float2 sc2[NP * 256];
    int tid = threadIdx.x, tx = blockIdx.x, b = blockIdx.y;
    int c = tx * CPB + tid;
    float u[CM];
    if (PASS == 0) {
        const float* x = in + (size_t)b * LX;
        float base = 2.0f * x[0] - x[PAD];
        load_uA(x, base, c, u);
    } else {
        const float* yb = in + (size_t)b * LPAD;
        load_uB(yb, yb[0], c, u);
    }
    float w1[NP], w2[NP];
    local_states(u, C, w1, w2);
    block_scan(sc2, tid, L, w1, w2);
    if (tid < NP)
        agg[(size_t)(b * NTROW + tx) * NP + tid] = sc2[tid * 256 + 255];
}

// ---------------------------------------------------------------------------
// K2: recompute local scan; combine predecessor tile aggregates (LDS-staged,
// 8-lane serial walk); replay with true entry state; coalesced store.
// PASS 0 -> ybuf reversed.  PASS 1 -> final out (un-reverse + trim).
template <int PASS>
__global__ __launch_bounds__(256) void k_full(const float* __restrict__ in,
                                              float* __restrict__ outp,
                                              const float2* __restrict__ agg,
                                              const float4* __restrict__ mt,
                                              CoeffsS C, LvS L) {
    __shared__ __align__(16) float lds[CPB * LDS_STRIDE];   // staging (aliases sc2)
    __shared__ float2 xa[CPB];      // predecessor aggregates
    __shared__ float2 xb[NP];       // tile entry state X
    float2* sc2 = reinterpret_cast<float2*>(lds);
    int tid = threadIdx.x, tx = blockIdx.x, b = blockIdx.y;
    int c = tx * CPB + tid;

    float u[CM];
    if (PASS == 0) {
        const float* x = in + (size_t)b * LX;
        float base = 2.0f * x[0] - x[PAD];
        load_uA(x, base, c, u);
    } else {
        const float* yb = in + (size_t)b * LPAD;
        load_uB(yb, yb[0], c, u);
    }
    float w1[NP], w2[NP];
    local_states(u, C, w1, w2);
    block_scan(sc2, tid, L, w1, w2);
    float e1[NP], e2[NP];            // exclusive local prefix (zero-init frame)
#pragma unroll
    for (int q = 0; q < NP; q++) {
        float2 ev = (tid > 0) ? sc2[q * 256 + tid - 1] : make_float2(0.f, 0.f);
        e1[q] = ev.x; e2[q] = ev.y;
    }

    // ---- tile prefix: cooperative load of tx*NP aggregates, 8-lane walk ----
    if (tid < tx * NP)
        xa[tid] = agg[(size_t)(b * NTROW + (tid >> 3)) * NP + (tid & 7)];
    __syncthreads();
    if (tid < NP) {
        int q = tid;
        float B0 = L.lv[8][q][0], B1 = L.lv[8][q][1];
        float B2 = L.lv[8][q][2], B3 = L.lv[8][q][3];
        float X1 = 0.f, X2 = 0.f;
        for (int j = 0; j < tx; j++) {
            float2 f = xa[j * NP + q];
            float n1 = fmaf(B0, X1, fmaf(B1, X2, f.x));
            float n2 = fmaf(B2, X1, fmaf(B3, X2, f.y));
            X1 = n1; X2 = n2;
        }
        xb[q] = make_float2(X1, X2);
    }
    __syncthreads();

    // ---- entry state = E + M0^tid * X; replay; stage to LDS ----
    {
        float4 m[NP];
#pragma unroll
        for (int q = 0; q < NP; q++) m[q] = mt[tid * NP + q];
#pragma unroll
        for (int q = 0; q < NP; q++) {
            float2 X = xb[q];
            w1[q] = fmaf(m[q].x, X.x, fmaf(m[q].y, X.y, e1[q]));
            w2[q] = fmaf(m[q].z, X.x, fmaf(m[q].w, X.y, e2[q]));
        }
#pragma unroll
        for (int i = 0; i < CM; i++) {
            float uu = u[i];
            float y = C.c0 * uu;
#pragma unroll
            for (int q = 0; q < NP; q++) {
                float wt = fmaf(C.a1[q], w1[q], fmaf(C.a2[q], w2[q], uu));
                y = fmaf(C.b0[q], wt, fmaf(C.b1[q], w1[q], y));
                w2[q] = w1[q]; w1[q] = wt;
            }
            u[i] = y;
        }
        if (PASS == 0) {
#pragma unroll
            for (int k = 0; k < CM / 2; k++)
                *reinterpret_cast<float2*>(&lds[tid * LDS_STRIDE + 2 * k]) =
                    make_float2(u[2 * k], u[2 * k + 1]);
        } else {
#pragma unroll
            for (int i = 0; i < CM; i++) lds[tid * LDS_STRIDE + i] = u[i];
        }
    }
    __syncthreads();

    if (PASS == 0) {
        // coalesced REVERSED store: ybuf[k] = y[LPAD-1-t'] (verified mapping)
        float4* ybase = reinterpret_cast<float4*>(
            outp + (size_t)b * LPAD + (size_t)(NTROW - 1 - tx) * TILE);
#pragma unroll
        for (int m = 0; m < 8; m++) {
            int o4 = m * CPB + tid;          // 0..2047
            int ts = 255 - (o4 >> 3);
            int ih = 31 - 4 * (o4 & 7);
            float2 a  = *reinterpret_cast<const float2*>(&lds[ts * LDS_STRIDE + ih - 1]);
            float2 b2 = *reinterpret_cast<const float2*>(&lds[ts * LDS_STRIDE + ih - 3]);
            ybase[o4] = make_float4(a.y, a.x, b2.y, b2.x);
        }
    } else {
        // out[j] = w[k], j = LTOT-1-PAD - k = 262194 - k (un-reverse + trim)
        float* ob = outp + (size_t)b * LX;
        int J0 = (LTOT - 1 - PAD) - tx * TILE;   // 262194 - 8192*tx
#pragma unroll
        for (int m = 0; m < CM; m++) {
            int o = m * CPB + tid;
            int j = J0 - o;
            if (j >= 0 && j < LX)
                ob[j] = lds[(o >> 5) * LDS_STRIDE + (o & 31)];
        }
    }
}

// ---------------------------------------------------------------------------
// Host: scipy butter(8,[500,7000]/8000,'bandpass') -> real 2nd-order sections
// + chunk-transition (A^CM) matrix power levels (f64, cast to f32).
// (HW-verified in round 8: absmax 0.015625.)
static void compute_coeffs(CoeffsS& C, LvS& L) {
    using cd = std::complex<double>;
    const int N = 8;
    const double sr = 16000.0, lo = 500.0, hi = 7000.0, fs = 2.0;
    double w0 = 2.0 * fs * std::tan(M_PI * (2.0 * lo / sr) / fs);
    double w1 = 2.0 * fs * std::tan(M_PI * (2.0 * hi / sr) / fs);
    double bw = w1 - w0, wo = std::sqrt(w0 * w1);
    cd pbp[16];
    for (int k = 0; k < N; k++) {
        int m = -N + 1 + 2 * k;
        cd pl = -std::exp(cd(0.0, M_PI * m / (2.0 * N)));
        pl *= bw / 2.0;
        cd s = std::sqrt(pl * pl - cd(wo * wo, 0.0));
        pbp[k] = pl + s; pbp[k + N] = pl - s;
    }
    double kbp = std::pow(bw, (double)N);
    const double fs2 = 4.0;
    cd pd[16], denom = 1.0;
    for (int i = 0; i < 16; i++) {
        pd[i] = (cd(fs2, 0.0) + pbp[i]) / (cd(fs2, 0.0) - pbp[i]);
        denom *= (cd(fs2, 0.0) - pbp[i]);
    }
    double kd = kbp * std::real(cd(std::pow(fs2, 8.0), 0.0) / denom);
    cd prodp = 1.0;
    for (int i = 0; i < 16; i++) prodp *= pd[i];
    cd c0 = cd(kd, 0.0) / prodp;
    int n = 0;
    for (int i = 0; i < 16; i++) {
        if (pd[i].imag() <= 0.0) continue;
        cd inv = 1.0 / pd[i];
        cd t1 = cd(1.0, 0.0) - inv, t2 = cd(1.0, 0.0) + inv;
        cd numr = cd(kd, 0.0);
        for (int k = 0; k < 8; k++) numr *= t1;
        for (int k = 0; k < 8; k++) numr *= t2;
        cd den = 1.0;
        for (int j = 0; j < 16; j++)
            if (j != i) den *= (cd(1.0, 0.0) - pd[j] * inv);
        cd r2 = 2.0 * numr / den;             // conjugate pair folded
        if (n < NP) {
            double a1 = 2.0 * pd[i].real();
            double a2 = -std::norm(pd[i]);
            C.a1[n] = (float)a1; C.a2[n] = (float)a2;
            C.b0[n] = (float)r2.real();
            C.b1[n] = (float)(-(r2.real() * pd[i].real() + r2.imag() * pd[i].imag()));
            double M[4] = { a1, a2, 1.0, 0.0 };       // A = [[a1,a2],[1,0]]
            for (int s = 0; s < 5; s++) {             // M0 = A^32
                double q0 = M[0] * M[0] + M[1] * M[2], q1 = M[0] * M[1] + M[1] * M[3];
                double q2 = M[2] * M[0] + M[3] * M[2], q3 = M[2] * M[1] + M[3] * M[3];
                M[0] = q0; M[1] = q1; M[2] = q2; M[3] = q3;
            }
            for (int k = 0; k < 9; k++) {             // lv[k] = M0^(2^k)
                for (int j = 0; j < 4; j++) L.lv[k][n][j] = (float)M[j];
                double q0 = M[0] * M[0] + M[1] * M[2], q1 = M[0] * M[1] + M[1] * M[3];
                double q2 = M[2] * M[0] + M[3] * M[2], q3 = M[2] * M[1] + M[3] * M[3];
                M[0] = q0; M[1] = q1; M[2] = q2; M[3] = q3;
            }
            n++;
        }
    }
    C.c0 = (float)c0.real();
}

extern "C" void kernel_launch(void* const* d_in, const int* in_sizes, int n_in,
                              void* d_out, int out_size, void* d_ws, size_t ws_size,
                              hipStream_t stream) {
    const float* audio = (const float*)d_in[0];
    float* out = (float*)d_out;

    CoeffsS C; LvS L;
    compute_coeffs(C, L);

    // ws: ybuf 34.6MB + mt 32KB + aggA/aggB 135KB each
    char* ws = (char*)d_ws;
    size_t o = 0;
    auto alloc = [&](size_t bytes) { size_t r = o; o += (bytes + 255) & ~(size_t)255; return r; };
    float*  ybuf = (float*)(ws + alloc((size_t)NB * LPAD * sizeof(float)));
    float4* mt   = (float4*)(ws + alloc(2048 * sizeof(float4)));
    float2* aggA = (float2*)(ws + alloc((size_t)NB * NTROW * NP * sizeof(float2)));
    float2* aggB = (float2*)(ws + alloc((size_t)NB * NTROW * NP * sizeof(float2)));

    dim3 blk(256), g(NTROW, NB);

    k_init   <<<8, 256, 0, stream>>>(mt, L);
    k_agg<0> <<<g, blk, 0, stream>>>(audio, aggA, C, L);
    k_full<0><<<g, blk, 0, stream>>>(audio, ybuf, aggA, mt, C, L);
    k_agg<1> <<<g, blk, 0, stream>>>(ybuf, aggB, C, L);
    k_full<1><<<g, blk, 0, stream>>>(ybuf, out, aggB, mt, C, L);
}

// Round 10
// 101.387 us; speedup vs baseline: 3.5179x; 1.0138x over previous
//
#include <hip/hip_runtime.h>
#include <cmath>
#include <complex>

// sr=16000, band 500-7000, order 8 -> 16 poles = 8 real 2nd-order sections.
#define NB    32
#define LX    262144
#define PAD   51                      // padlen = 3*17
#define LTOT  (LX + 2 * PAD)          // 262246
#define CM    32                      // samples per chunk (= per thread)
#define F_PAD 8090                    // zero-input front pad
#define LPAD  (LTOT + F_PAD)          // 270336 = 33 * 8192 (tile-aligned)
#define NCK   (LPAD / CM)             // 8448 chunks per row (all full)
#define CPB   256                     // chunks (threads) per tile
#define TILE  (CPB * CM)              // 8192 samples per tile
#define NTROW (LPAD / TILE)           // 33 tiles per row
#define NP    8
#define LDS_STRIDE 34

struct CoeffsS { float a1[NP], a2[NP], b0[NP], b1[NP], gss[NP], c0; };
// lv[k][q] = (A_q^CM)^(2^k) = M0^(2^k); lv[8] = M0^256 = tile transition
struct LvS { float lv[9][NP][4]; };

// ---------------------------------------------------------------------------
// init: build mt[t][q] = M0^t (t=0..255) via binary exponentiation.
__global__ void k_init(float4* __restrict__ mt, LvS L) {
    int id = blockIdx.x * 256 + threadIdx.x;          // 0..2047
    int t = id >> 3, q = id & 7;
    float m0 = 1.f, m1 = 0.f, m2 = 0.f, m3 = 1.f;
    for (int k = 0; k < 8; k++)
        if ((t >> k) & 1) {
            float a0 = L.lv[k][q][0], a1 = L.lv[k][q][1];
            float a2 = L.lv[k][q][2], a3 = L.lv[k][q][3];
            float n0 = a0 * m0 + a1 * m2, n1 = a0 * m1 + a1 * m3;
            float n2 = a2 * m0 + a3 * m2, n3 = a2 * m1 + a3 * m3;
            m0 = n0; m1 = n1; m2 = n2; m3 = n3;
        }
    mt[id] = make_float4(m0, m1, m2, m3);
}

// ---------------------------------------------------------------------------
// u-loaders. PASS A: global sample t' = c*CM + i, real time t = t' - F_PAD;
// u = 0 in the front pad, else ext[t] - ext[0] (odd extension of audio).
__device__ __forceinline__ void load_uA(const float* __restrict__ x,
                                        float base, int c, float (&u)[CM]) {
    int t0 = c * CM - F_PAD;
    if (t0 >= PAD && t0 + CM <= PAD + LX) {
        const float* xs = x + (t0 - PAD);
#pragma unroll
        for (int m = 0; m < CM / 4; m++) {
            float4 v = *reinterpret_cast<const float4*>(xs + 4 * m);
            u[4 * m] = v.x - base; u[4 * m + 1] = v.y - base;
            u[4 * m + 2] = v.z - base; u[4 * m + 3] = v.w - base;
        }
    } else {
#pragma unroll
        for (int i = 0; i < CM; i++) {
            int t = t0 + i;
            float uu;
            if (t < 0) uu = 0.f;                        // front pad
            else {
                float e;
                if (t < PAD)            e = 2.0f * x[0] - x[PAD - t];
                else if (t < PAD + LX)  e = x[t - PAD];
                else                    e = 2.0f * x[LX - 1] - x[2 * LX + PAD - 2 - t];
                uu = e - base;
            }
            u[i] = uu;
        }
    }
}

// PASS B: in = ybuf row (reversed y); base = ybuf[0] = y[LTOT-1].
__device__ __forceinline__ void load_uB(const float* __restrict__ yb,
                                        float base, int c, float (&u)[CM]) {
#pragma unroll
    for (int m = 0; m < CM / 4; m++) {
        float4 v = *reinterpret_cast<const float4*>(yb + (size_t)c * CM + 4 * m);
        u[4 * m] = v.x - base; u[4 * m + 1] = v.y - base;
        u[4 * m + 2] = v.z - base; u[4 * m + 3] = v.w - base;
    }
}

// local chunk recurrence from zero state
__device__ __forceinline__ void local_states(const float (&u)[CM], const CoeffsS& C,
                                             float (&w1)[NP], float (&w2)[NP]) {
#pragma unroll
    for (int q = 0; q < NP; q++) { w1[q] = 0.f; w2[q] = 0.f; }
#pragma unroll
    for (int i = 0; i < CM; i++) {
        float uu = u[i];
#pragma unroll
        for (int q = 0; q < NP; q++) {
            float wt = fmaf(C.a1[q], w1[q], fmaf(C.a2[q], w2[q], uu));
            w2[q] = w1[q]; w1[q] = wt;
        }
    }
}

// block-level Hillis-Steele inclusive affine scan; `pos` = this thread's
// sequence position (0..255). All threads must participate (barriers).
__device__ __forceinline__ void block_scan(float2* sc2, int pos, const LvS& L,
                                           float (&w1)[NP], float (&w2)[NP]) {
#pragma unroll
    for (int q = 0; q < NP; q++) sc2[q * 256 + pos] = make_float2(w1[q], w2[q]);
    __syncthreads();
#pragma unroll
    for (int k = 0; k < 8; k++) {
        int d = 1 << k;
        float2 o[NP];
        if (pos >= d) {
#pragma unroll
            for (int q = 0; q < NP; q++) o[q] = sc2[q * 256 + pos - d];
        }
        __syncthreads();
        if (pos >= d) {
#pragma unroll
            for (int q = 0; q < NP; q++) {
                w1[q] = fmaf(L.lv[k][q][0], o[q].x, fmaf(L.lv[k][q][1], o[q].y, w1[q]));
                w2[q] = fmaf(L.lv[k][q][2], o[q].x, fmaf(L.lv[k][q][3], o[q].y, w2[q]));
            }
        }
#pragma unroll
        for (int q = 0; q < NP; q++) sc2[q * 256 + pos] = make_float2(w1[q], w2[q]);
        __syncthreads();
    }
}

// ---------------------------------------------------------------------------
// K1 (pass A only): per-tile aggregates from zero init.
__global__ __launch_bounds__(256) void k_agg(const float* __restrict__ in,
                                             float2* __restrict__ agg,
                                             CoeffsS C, LvS L) {
    __shared__ float2 sc2[NP * 256];
    int tid = threadIdx.x, tx = blockIdx.x, b = blockIdx.y;
    const float* x = in + (size_t)b * LX;
    float base = 2.0f * x[0] - x[PAD];
    float u[CM];
    load_uA(x, base, tx * CPB + tid, u);
    float w1[NP], w2[NP];
    local_states(u, C, w1, w2);
    block_scan(sc2, tid, L, w1, w2);
    if (tid < NP)
        agg[(size_t)(b * NTROW + tx) * NP + tid] = sc2[tid * 256 + 255];
}

// ---------------------------------------------------------------------------
// K2: local scan; predecessor-aggregate combine; replay; coalesced store.
// PASS 0: in=audio -> ybuf reversed; ALSO emits raw pass-B tile aggregates
//         (reverse recurrence over register y; base correction deferred).
// PASS 1: in=ybuf -> final out (un-reverse + trim); corrects aggregates by
//         base*gss in the prefix walk.
template <int PASS>
__global__ __launch_bounds__(256) void k_full(const float* __restrict__ in,
                                              float* __restrict__ outp,
                                              const float2* __restrict__ agg,
                                              float2* __restrict__ aggB,
                                              const float4* __restrict__ mt,
                                              CoeffsS C, LvS L) {
    __shared__ __align__(16) float lds[CPB * LDS_STRIDE];   // staging (aliases sc2)
    __shared__ float2 xa[CPB];      // predecessor aggregates
    __shared__ float2 xb[NP];       // tile entry state X
    float2* sc2 = reinterpret_cast<float2*>(lds);
    int tid = threadIdx.x, tx = blockIdx.x, b = blockIdx.y;
    int c = tx * CPB + tid;

    float u[CM];
    if (PASS == 0) {
        const float* x = in + (size_t)b * LX;
        float base = 2.0f * x[0] - x[PAD];
        load_uA(x, base, c, u);
    } else {
        const float* yb = in + (size_t)b * LPAD;
        load_uB(yb, yb[0], c, u);
    }
    float w1[NP], w2[NP];
    local_states(u, C, w1, w2);
    block_scan(sc2, tid, L, w1, w2);
    float e1[NP], e2[NP];            // exclusive local prefix
#pragma unroll
    for (int q = 0; q < NP; q++) {
        float2 ev = (tid > 0) ? sc2[q * 256 + tid - 1] : make_float2(0.f, 0.f);
        e1[q] = ev.x; e2[q] = ev.y;
    }

    // ---- tile prefix: cooperative load of tx*NP aggregates, 8-lane walk ----
    if (tid < tx * NP)
        xa[tid] = agg[(size_t)(b * NTROW + (tid >> 3)) * NP + (tid & 7)];
    __syncthreads();
    if (tid < NP) {
        int q = tid;
        float B0 = L.lv[8][q][0], B1 = L.lv[8][q][1];
        float B2 = L.lv[8][q][2], B3 = L.lv[8][q][3];
        float cg = 0.f;
        if (PASS == 1) cg = in[(size_t)b * LPAD] * C.gss[q];   // base * G8192
        float X1 = 0.f, X2 = 0.f;
        for (int j = 0; j < tx; j++) {
            float2 f = xa[j * NP + q];
            float n1 = fmaf(B0, X1, fmaf(B1, X2, f.x - cg));
            float n2 = fmaf(B2, X1, fmaf(B3, X2, f.y - cg));
            X1 = n1; X2 = n2;
        }
        xb[q] = make_float2(X1, X2);
    }
    __syncthreads();

    // ---- entry state = E + M0^tid * X; replay (u -> y in registers) ----
    {
        float4 m[NP];
#pragma unroll
        for (int q = 0; q < NP; q++) m[q] = mt[tid * NP + q];
#pragma unroll
        for (int q = 0; q < NP; q++) {
            float2 X = xb[q];
            w1[q] = fmaf(m[q].x, X.x, fmaf(m[q].y, X.y, e1[q]));
            w2[q] = fmaf(m[q].z, X.x, fmaf(m[q].w, X.y, e2[q]));
        }
#pragma unroll
        for (int i = 0; i < CM; i++) {
            float uu = u[i];
            float y = C.c0 * uu;
#pragma unroll
            for (int q = 0; q < NP; q++) {
                float wt = fmaf(C.a1[q], w1[q], fmaf(C.a2[q], w2[q], uu));
                y = fmaf(C.b0[q], wt, fmaf(C.b1[q], w1[q], y));
                w2[q] = w1[q]; w1[q] = wt;
            }
            u[i] = y;
        }
    }

    if (PASS == 0) {
        // ---- fused: RAW pass-B local chunk states over reversed register y.
        // This thread's forward chunk c IS pass-B chunk of tile 32-tx, pos 255-tid.
        float t1[NP], t2[NP];
#pragma unroll
        for (int q = 0; q < NP; q++) { t1[q] = 0.f; t2[q] = 0.f; }
#pragma unroll
        for (int i = CM - 1; i >= 0; --i) {
            float wv = u[i];
#pragma unroll
            for (int q = 0; q < NP; q++) {
                float wt = fmaf(C.a1[q], t1[q], fmaf(C.a2[q], t2[q], wv));
                t2[q] = t1[q]; t1[q] = wt;
            }
        }
        __syncthreads();                       // sc2 free for reuse
        block_scan(sc2, 255 - tid, L, t1, t2);
        if (tid < NP)
            aggB[(size_t)(b * NTROW + (NTROW - 1 - tx)) * NP + tid] =
                sc2[tid * 256 + 255];
        __syncthreads();                       // before staging overwrites sc2
    }

    // ---- stage y to LDS; coalesced store ----
    if (PASS == 0) {
#pragma unroll
        for (int k = 0; k < CM / 2; k++)
            *reinterpret_cast<float2*>(&lds[tid * LDS_STRIDE + 2 * k]) =
                make_float2(u[2 * k], u[2 * k + 1]);
    } else {
#pragma unroll
        for (int i = 0; i < CM; i++) lds[tid * LDS_STRIDE + i] = u[i];
    }
    __syncthreads();

    if (PASS == 0) {
        // coalesced REVERSED store: ybuf[k] = y[LPAD-1-t']
        float4* ybase = reinterpret_cast<float4*>(
            outp + (size_t)b * LPAD + (size_t)(NTROW - 1 - tx) * TILE);
#pragma unroll
        for (int m = 0; m < 8; m++) {
            int o4 = m * CPB + tid;          // 0..2047
            int ts = 255 - (o4 >> 3);
            int ih = 31 - 4 * (o4 & 7);
            float2 a  = *reinterpret_cast<const float2*>(&lds[ts * LDS_STRIDE + ih - 1]);
            float2 b2 = *reinterpret_cast<const float2*>(&lds[ts * LDS_STRIDE + ih - 3]);
            ybase[o4] = make_float4(a.y, a.x, b2.y, b2.x);
        }
    } else {
        // out[j] = w[k], j = LTOT-1-PAD - k = 262194 - k (un-reverse + trim)
        float* ob = outp + (size_t)b * LX;
        int J0 = (LTOT - 1 - PAD) - tx * TILE;
#pragma unroll
        for (int m = 0; m < CM; m++) {
            int o = m * CPB + tid;
            int j = J0 - o;
            if (j >= 0 && j < LX)
                ob[j] = lds[(o >> 5) * LDS_STRIDE + (o & 31)];
        }
    }
}

// ---------------------------------------------------------------------------
// Host: scipy butter(8,[500,7000]/8000,'bandpass') -> real 2nd-order sections
// + chunk-transition (A^CM) matrix power levels + steady-state gss (f64).
static void compute_coeffs(CoeffsS& C, LvS& L) {
    using cd = std::complex<double>;
    const int N = 8;
    const double sr = 16000.0, lo = 500.0, hi = 7000.0, fs = 2.0;
    double w0 = 2.0 * fs * std::tan(M_PI * (2.0 * lo / sr) / fs);
    double w1 = 2.0 * fs * std::tan(M_PI * (2.0 * hi / sr) / fs);
    double bw = w1 - w0, wo = std::sqrt(w0 * w1);
    cd pbp[16];
    for (int k = 0; k < N; k++) {
        int m = -N + 1 + 2 * k;
        cd pl = -std::exp(cd(0.0, M_PI * m / (2.0 * N)));
        pl *= bw / 2.0;
        cd s = std::sqrt(pl * pl - cd(wo * wo, 0.0));
        pbp[k] = pl + s; pbp[k + N] = pl - s;
    }
    double kbp = std::pow(bw, (double)N);
    const double fs2 = 4.0;
    cd pd[16], denom = 1.0;
    for (int i = 0; i < 16; i++) {
        pd[i] = (cd(fs2, 0.0) + pbp[i]) / (cd(fs2, 0.0) - pbp[i]);
        denom *= (cd(fs2, 0.0) - pbp[i]);
    }
    double kd = kbp * std::real(cd(std::pow(fs2, 8.0), 0.0) / denom);
    cd prodp = 1.0;
    for (int i = 0; i < 16; i++) prodp *= pd[i];
    cd c0 = cd(kd, 0.0) / prodp;
    int n = 0;
    for (int i = 0; i < 16; i++) {
        if (pd[i].imag() <= 0.0) continue;
        cd inv = 1.0 / pd[i];
        cd t1 = cd(1.0, 0.0) - inv, t2 = cd(1.0, 0.0) + inv;
        cd numr = cd(kd, 0.0);
        for (int k = 0; k < 8; k++) numr *= t1;
        for (int k = 0; k < 8; k++) numr *= t2;
        cd den = 1.0;
        for (int j = 0; j < 16; j++)
            if (j != i) den *= (cd(1.0, 0.0) - pd[j] * inv);
        cd r2 = 2.0 * numr / den;             // conjugate pair folded
        if (n < NP) {
            double a1 = 2.0 * pd[i].real();
            double a2 = -std::norm(pd[i]);
            C.a1[n] = (float)a1; C.a2[n] = (float)a2;
            C.b0[n] = (float)r2.real();
            C.b1[n] = (float)(-(r2.real() * pd[i].real() + r2.imag() * pd[i].imag()));
            C.gss[n] = (float)(1.0 / (1.0 - a1 - a2));   // G8192 steady state
            double M[4] = { a1, a2, 1.0, 0.0 };          // A = [[a1,a2],[1,0]]
            for (int s = 0; s < 5; s++) {                // M0 = A^32
                double q0 = M[0] * M[0] + M[1] * M[2], q1 = M[0] * M[1] + M[1] * M[3];
                double q2 = M[2] * M[0] + M[3] * M[2], q3 = M[2] * M[1] + M[3] * M[3];
                M[0] = q0; M[1] = q1; M[2] = q2; M[3] = q3;
            }
            for (int k = 0; k < 9; k++) {                // lv[k] = M0^(2^k)
                for (int j = 0; j < 4; j++) L.lv[k][n][j] = (float)M[j];
                double q0 = M[0] * M[0] + M[1] * M[2], q1 = M[0] * M[1] + M[1] * M[3];
                double q2 = M[2] * M[0] + M[3] * M[2], q3 = M[2] * M[1] + M[3] * M[3];
                M[0] = q0; M[1] = q1; M[2] = q2; M[3] = q3;
            }
            n++;
        }
    }
    C.c0 = (float)c0.real();
}

extern "C" void kernel_launch(void* const* d_in, const int* in_sizes, int n_in,
                              void* d_out, int out_size, void* d_ws, size_t ws_size,
                              hipStream_t stream) {
    const float* audio = (const float*)d_in[0];
    float* out = (float*)d_out;

    CoeffsS C; LvS L;
    compute_coeffs(C, L);

    // ws: ybuf 34.6MB + mt 32KB + aggA/aggB 135KB each
    char* ws = (char*)d_ws;
    size_t o = 0;
    auto alloc = [&](size_t bytes) { size_t r = o; o += (bytes + 255) & ~(size_t)255; return r; };
    float*  ybuf = (float*)(ws + alloc((size_t)NB * LPAD * sizeof(float)));
    float4* mt   = (float4*)(ws + alloc(2048 * sizeof(float4)));
    float2* aggA = (float2*)(ws + alloc((size_t)NB * NTROW * NP * sizeof(float2)));
    float2* aggB = (float2*)(ws + alloc((size_t)NB * NTROW * NP * sizeof(float2)));

    dim3 blk(256), g(NTROW, NB);

    k_init   <<<8, 256, 0, stream>>>(mt, L);
    k_agg    <<<g, blk, 0, stream>>>(audio, aggA, C, L);
    k_full<0><<<g, blk, 0, stream>>>(audio, ybuf, aggA, aggB, mt, C, L);
    k_full<1><<<g, blk, 0, stream>>>(ybuf, out, aggB, nullptr, mt, C, L);
}